// Round 2
// baseline (775.097 us; speedup 1.0000x reference)
//
#include <hip/hip_runtime.h>
#include <math.h>

// AngularSoftmax: B=256, F=512, C=100000, M=4 (k=3), fp32.
// out[b,c] = log(e_psi / (e_psi + total_b - e_cos))
//          = x_psi - log(exp(x_psi) + (total_b - e_cos))   <- stable log-space form
// with Wn = W / ||W||_rows (axis=1!), xw = x @ Wn, cos = xw/(|x|+eps),
//   psi = -(8c^4-8c^2+1) - 6, x_psi = |x|*psi, total = sum_c exp(|x|*cos).
// Fold 1/||W_f|| into x (x' = x * inv_norm[f]) so the GEMM reads raw W.

#define BATCH   256
#define FEAT    512
#define CLASSES 100000
#define EPSV    1e-6f

// ---------------- K1: inv_norm[f] = 1/sqrt(sum_c W[f,c]^2) ----------------
__global__ void winorm_kernel(const float* __restrict__ W, float* __restrict__ inv_norm) {
    const int f = blockIdx.x;
    const float4* row = reinterpret_cast<const float4*>(W + (size_t)f * CLASSES);
    float s = 0.f;
    for (int i = threadIdx.x; i < CLASSES / 4; i += blockDim.x) {
        float4 v = row[i];
        s += v.x * v.x + v.y * v.y + v.z * v.z + v.w * v.w;
    }
    __shared__ float red[4];
    #pragma unroll
    for (int off = 32; off > 0; off >>= 1) s += __shfl_down(s, off);
    const int lane = threadIdx.x & 63, wid = threadIdx.x >> 6;
    if (lane == 0) red[wid] = s;
    __syncthreads();
    if (threadIdx.x == 0) {
        float t = red[0] + red[1] + red[2] + red[3];
        inv_norm[f] = 1.0f / sqrtf(t);
    }
}

// ---------------- K2: x' = x * inv_norm, modx[b] = ||x_b|| ----------------
__global__ void xprep_kernel(const float* __restrict__ x, const float* __restrict__ inv_norm,
                             float* __restrict__ xprime, float* __restrict__ modx) {
    const int b = blockIdx.x;      // 256 blocks
    const int t = threadIdx.x;     // 128 threads, one float4 each (FEAT/4 = 128)
    float4 xv = reinterpret_cast<const float4*>(x + (size_t)b * FEAT)[t];
    float s = xv.x * xv.x + xv.y * xv.y + xv.z * xv.z + xv.w * xv.w;
    __shared__ float red[2];
    #pragma unroll
    for (int off = 32; off > 0; off >>= 1) s += __shfl_down(s, off);
    const int lane = t & 63, wid = t >> 6;
    if (lane == 0) red[wid] = s;
    __syncthreads();
    if (t == 0) modx[b] = sqrtf(red[0] + red[1]);
    float4 iv = reinterpret_cast<const float4*>(inv_norm)[t];
    float4 o;
    o.x = xv.x * iv.x; o.y = xv.y * iv.y; o.z = xv.z * iv.z; o.w = xv.w * iv.w;
    reinterpret_cast<float4*>(xprime + (size_t)b * FEAT)[t] = o;
}

// ---------------- K3: GEMM  C[256,100000] = x'[256,512] @ W[512,100000] ----------------
#define BM 64
#define BN 128
#define BK 32
#define TM 4
#define TN 8
// 256 threads = 16 thread-rows x 16 thread-cols; thread tile 4x8.

__global__ __launch_bounds__(256) void gemm_kernel(const float* __restrict__ A,
                                                   const float* __restrict__ B,
                                                   float* __restrict__ C) {
    __shared__ float As[BK][BM];   // A stored transposed: As[k][m]
    __shared__ float Bs[BK][BN];
    const int tid = threadIdx.x;
    const int m0 = blockIdx.y * BM;
    const int n0 = blockIdx.x * BN;
    const int tr = tid >> 4;       // 0..15
    const int tc = tid & 15;       // 0..15

    float acc[TM][TN] = {};

    for (int k0 = 0; k0 < FEAT; k0 += BK) {
        // A tile: 64x32 floats = 512 float4 (vector along k), 2 per thread.
        #pragma unroll
        for (int l = 0; l < 2; ++l) {
            int p = tid + l * 256;
            int m = p >> 3, kq = p & 7;
            float4 v = *reinterpret_cast<const float4*>(A + (size_t)(m0 + m) * FEAT + k0 + kq * 4);
            As[kq * 4 + 0][m] = v.x;
            As[kq * 4 + 1][m] = v.y;
            As[kq * 4 + 2][m] = v.z;
            As[kq * 4 + 3][m] = v.w;
        }
        // B tile: 32x128 floats = 1024 float4 (vector along c), 4 per thread.
        #pragma unroll
        for (int l = 0; l < 4; ++l) {
            int p = tid + l * 256;
            int k = p >> 5, cq = p & 31;
            int c = n0 + cq * 4;
            float4 v = make_float4(0.f, 0.f, 0.f, 0.f);
            if (c + 4 <= CLASSES)
                v = *reinterpret_cast<const float4*>(B + (size_t)(k0 + k) * CLASSES + c);
            *reinterpret_cast<float4*>(&Bs[k][cq * 4]) = v;
        }
        __syncthreads();
        #pragma unroll
        for (int k = 0; k < BK; ++k) {
            float4 a4  = *reinterpret_cast<const float4*>(&As[k][tr * TM]);
            float4 b04 = *reinterpret_cast<const float4*>(&Bs[k][tc * TN]);
            float4 b14 = *reinterpret_cast<const float4*>(&Bs[k][tc * TN + 4]);
            float av[TM] = {a4.x, a4.y, a4.z, a4.w};
            float bv[TN] = {b04.x, b04.y, b04.z, b04.w, b14.x, b14.y, b14.z, b14.w};
            #pragma unroll
            for (int mi = 0; mi < TM; ++mi)
                #pragma unroll
                for (int ni = 0; ni < TN; ++ni)
                    acc[mi][ni] = fmaf(av[mi], bv[ni], acc[mi][ni]);
        }
        __syncthreads();
    }

    #pragma unroll
    for (int mi = 0; mi < TM; ++mi) {
        float* crow = C + (size_t)(m0 + tr * TM + mi) * CLASSES;
        int c = n0 + tc * TN;
        if (c + 4 <= CLASSES)
            *reinterpret_cast<float4*>(crow + c) =
                make_float4(acc[mi][0], acc[mi][1], acc[mi][2], acc[mi][3]);
        if (c + 8 <= CLASSES)
            *reinterpret_cast<float4*>(crow + c + 4) =
                make_float4(acc[mi][4], acc[mi][5], acc[mi][6], acc[mi][7]);
    }
}

// ---------------- K4: totals[b] = sum_c exp(modx * (xw/(modx+eps))) ----------------
__global__ void totals_kernel(const float* __restrict__ xw, const float* __restrict__ modx,
                              float* __restrict__ totals) {
    const int b = blockIdx.x;
    const float mx = modx[b];
    const float inv_me = 1.0f / (mx + EPSV);
    const float4* row = reinterpret_cast<const float4*>(xw + (size_t)b * CLASSES);
    float s = 0.f;
    for (int i = threadIdx.x; i < CLASSES / 4; i += blockDim.x) {
        float4 v = row[i];
        s += expf(mx * (v.x * inv_me));
        s += expf(mx * (v.y * inv_me));
        s += expf(mx * (v.z * inv_me));
        s += expf(mx * (v.w * inv_me));
    }
    __shared__ float red[4];
    #pragma unroll
    for (int off = 32; off > 0; off >>= 1) s += __shfl_down(s, off);
    const int lane = threadIdx.x & 63, wid = threadIdx.x >> 6;
    if (lane == 0) red[wid] = s;
    __syncthreads();
    if (threadIdx.x == 0) totals[b] = red[0] + red[1] + red[2] + red[3];
}

// ---------------- K5: final epilogue (stable log-space), in-place on d_out ----------------
__global__ void final_kernel(float* __restrict__ xw, const float* __restrict__ modx,
                             const float* __restrict__ totals) {
    const int b = blockIdx.y;
    const int i = blockIdx.x * blockDim.x + threadIdx.x;   // float4 index
    if (i >= CLASSES / 4) return;
    const float mx = modx[b];
    const float tot = totals[b];
    const float inv_me = 1.0f / (mx + EPSV);
    float4* row = reinterpret_cast<float4*>(xw + (size_t)b * CLASSES);
    float4 v = row[i];
    float r[4] = {v.x, v.y, v.z, v.w};
    #pragma unroll
    for (int j = 0; j < 4; ++j) {
        float ct   = r[j] * inv_me;          // cos_theta
        float xct  = mx * ct;                // x_cos_theta
        float ec   = expf(xct);              // e_cos
        float c2   = ct * ct;
        float cm   = 8.f * c2 * c2 - 8.f * c2 + 1.f;   // cos(4t)
        float psi  = -cm - 6.f;              // (-1)^3 * cm - 2*3
        float xpsi = mx * psi;               // ~ -158, exp underflows in fp32
        // log(e_psi/(e_psi+tot-ec)) = xpsi - log(exp(xpsi) + (tot-ec)); arg > 0 always
        float den  = expf(xpsi) + (tot - ec);
        r[j] = xpsi - logf(den);
    }
    row[i] = make_float4(r[0], r[1], r[2], r[3]);
}

extern "C" void kernel_launch(void* const* d_in, const int* in_sizes, int n_in,
                              void* d_out, int out_size, void* d_ws, size_t ws_size,
                              hipStream_t stream) {
    const float* x = (const float*)d_in[0];   // [256, 512]
    const float* W = (const float*)d_in[1];   // [512, 100000]
    float* out = (float*)d_out;               // [256, 100000]
    float* ws  = (float*)d_ws;

    float* xprime   = ws;                     // 256*512 = 131072 floats
    float* inv_norm = ws + 131072;            // 512
    float* modx     = ws + 131584;            // 256
    float* totals   = ws + 131840;            // 256

    winorm_kernel<<<FEAT, 256, 0, stream>>>(W, inv_norm);
    xprep_kernel<<<BATCH, 128, 0, stream>>>(x, inv_norm, xprime, modx);
    gemm_kernel<<<dim3((CLASSES + BN - 1) / BN, BATCH / BM), 256, 0, stream>>>(xprime, W, out);
    totals_kernel<<<BATCH, 256, 0, stream>>>(out, modx, totals);
    final_kernel<<<dim3((CLASSES / 4 + 255) / 256, BATCH), 256, 0, stream>>>(out, modx, totals);
}

// Round 6
// 614.275 us; speedup vs baseline: 1.2618x; 1.2618x over previous
//
#include <hip/hip_runtime.h>
#include <math.h>

// AngularSoftmax: B=256, F=512, C=100000, M=4 (k=3), fp32 in/out.
// out[b,c] = x_psi - log(exp(x_psi) + (total_b - e_cos))   (stable log-space)
// Round 6: FIX round-5 bug — B-tile LDS staging only covered 64/128 columns
// (bc4=tid&15 spans 16*4=64 cols); cols 64..127 of Bs were uninitialized ->
// NaN bf16 garbage -> NaN outputs. Now 2 staging rounds cover the full tile.
// Also: clamp ct/tot/den so no garbage path can ever emit NaN or -inf.

#define BATCH   256
#define FEAT    512
#define CLASSES 100000
#define EPSV    1e-6f
#define BN      128
#define BK      32

typedef __attribute__((ext_vector_type(8))) short short8v;   // 8 bf16 (4 VGPRs)
typedef __attribute__((ext_vector_type(4))) float f32x4;

static __device__ __forceinline__ unsigned short f32_to_bf16(float f) {
    unsigned int u = __float_as_uint(f);
    u += 0x7fffu + ((u >> 16) & 1u);     // RNE (inputs are finite)
    return (unsigned short)(u >> 16);
}

// ---------------- K1: inv_norm[f] = 1/sqrt(sum_c W[f,c]^2) ----------------
__global__ __launch_bounds__(512) void winorm_kernel(const float* __restrict__ W,
                                                     float* __restrict__ inv_norm) {
    const int f = blockIdx.x;
    const float4* row = reinterpret_cast<const float4*>(W + (size_t)f * CLASSES);
    float s = 0.f;
    for (int i = threadIdx.x; i < CLASSES / 4; i += blockDim.x) {
        float4 v = row[i];
        s += v.x * v.x + v.y * v.y + v.z * v.z + v.w * v.w;
    }
    __shared__ float red[8];
    #pragma unroll
    for (int off = 32; off > 0; off >>= 1) s += __shfl_down(s, off);
    const int lane = threadIdx.x & 63, wid = threadIdx.x >> 6;
    if (lane == 0) red[wid] = s;
    __syncthreads();
    if (threadIdx.x == 0) {
        float t = 0.f;
        #pragma unroll
        for (int i = 0; i < 8; ++i) t += red[i];
        inv_norm[f] = 1.0f / sqrtf(t);
    }
}

// ---------------- K2: xp = bf16(x * inv_norm), modx[b] = ||x_b||, zero totals ----------------
__global__ void xprep_kernel(const float* __restrict__ x, const float* __restrict__ inv_norm,
                             unsigned short* __restrict__ xp, float* __restrict__ modx,
                             float* __restrict__ totals) {
    const int b = blockIdx.x;      // 256 blocks
    const int t = threadIdx.x;     // 128 threads, one float4 each
    float4 xv = reinterpret_cast<const float4*>(x + (size_t)b * FEAT)[t];
    float s = xv.x * xv.x + xv.y * xv.y + xv.z * xv.z + xv.w * xv.w;
    __shared__ float red[2];
    #pragma unroll
    for (int off = 32; off > 0; off >>= 1) s += __shfl_down(s, off);
    const int lane = t & 63, wid = t >> 6;
    if (lane == 0) red[wid] = s;
    __syncthreads();
    if (t == 0) { modx[b] = sqrtf(red[0] + red[1]); totals[b] = 0.f; }
    float4 iv = reinterpret_cast<const float4*>(inv_norm)[t];
    ushort4 o;
    o.x = f32_to_bf16(xv.x * iv.x);
    o.y = f32_to_bf16(xv.y * iv.y);
    o.z = f32_to_bf16(xv.z * iv.z);
    o.w = f32_to_bf16(xv.w * iv.w);
    reinterpret_cast<ushort4*>(xp + (size_t)b * FEAT)[t] = o;
}

// ---------------- K3: MFMA GEMM  xw[256,100000] = xp @ W  + fused e_cos totals ----------------
// BM=256 (whole batch, W read once), BN=128, BK=32. 512 threads = 8 waves (4M x 2N).
// As[256][32] m-major (linear b128 stage), Bs[128][32] c-major (reg-staged transpose+cvt).
__global__ __launch_bounds__(512) void gemm_kernel(
        const unsigned short* __restrict__ xp,  // [256][512] bf16
        const float* __restrict__ W,            // [512][100000] fp32
        const float* __restrict__ modx,         // [256]
        float* __restrict__ out,                // [256][100000] <- xw
        float* __restrict__ totals)             // [256]
{
    __shared__ __align__(16) unsigned short As[BATCH * BK];
    __shared__ __align__(16) unsigned short Bs[BN * BK];
    __shared__ float s_modx[BATCH], s_inv[BATCH];

    const int tid  = threadIdx.x;
    const int wave = tid >> 6;
    const int lane = tid & 63;
    const int c0   = blockIdx.x * BN;

    if (tid < BATCH) {
        float m = modx[tid];
        s_modx[tid] = m;
        s_inv[tid]  = 1.0f / (m + EPSV);
    }

    const int wm = wave >> 1;          // 0..3 -> rows [wm*64, +64)
    const int wn = wave & 1;           // 0..1 -> cols [wn*64, +64)

    // A staging: 2 rounds; row = rnd*128 + (tid>>2), k-chunk = tid&3 (8 bf16 = 16B)
    const int ra = tid >> 2, qa = tid & 3;
    // B staging: col group bc4 = tid&31 (32 groups * 4 cols = 128 cols = BN),
    // k row = (tid>>5) + rnd*16  -> 2 rounds cover all 32 k rows. FULL tile.
    const int bc4 = tid & 31, bk0 = tid >> 5;
    int cbase = c0 + bc4 * 4;
    if (cbase > CLASSES - 4) cbase = CLASSES - 4;   // clamp; junk cols masked in epilogue

    f32x4 acc[4][4];
    #pragma unroll
    for (int i = 0; i < 4; ++i)
        #pragma unroll
        for (int j = 0; j < 4; ++j) acc[i][j] = (f32x4){0.f, 0.f, 0.f, 0.f};

    for (int k0 = 0; k0 < FEAT; k0 += BK) {
        // ---- stage A (linear, conflict-free b128 writes) ----
        #pragma unroll
        for (int rnd = 0; rnd < 2; ++rnd) {
            int r = rnd * 128 + ra;
            short8v v = *reinterpret_cast<const short8v*>(xp + (size_t)r * FEAT + k0 + qa * 8);
            *reinterpret_cast<short8v*>(&As[r * BK + qa * 8]) = v;
        }
        // ---- stage B (coalesced float4 read, cvt, transposed scalar writes) ----
        #pragma unroll
        for (int rnd = 0; rnd < 2; ++rnd) {
            int kk = bk0 + rnd * 16;
            float4 wv = *reinterpret_cast<const float4*>(W + (size_t)(k0 + kk) * CLASSES + cbase);
            Bs[(bc4 * 4 + 0) * BK + kk] = f32_to_bf16(wv.x);
            Bs[(bc4 * 4 + 1) * BK + kk] = f32_to_bf16(wv.y);
            Bs[(bc4 * 4 + 2) * BK + kk] = f32_to_bf16(wv.z);
            Bs[(bc4 * 4 + 3) * BK + kk] = f32_to_bf16(wv.w);
        }
        __syncthreads();
        // ---- fragments + 16 MFMA ----
        const int fr = lane & 15, kc = lane >> 4;   // row-in-frag, k-chunk
        short8v af[4];
        #pragma unroll
        for (int mi = 0; mi < 4; ++mi)
            af[mi] = *reinterpret_cast<const short8v*>(&As[(wm * 64 + mi * 16 + fr) * BK + kc * 8]);
        #pragma unroll
        for (int ni = 0; ni < 4; ++ni) {
            short8v bfrag = *reinterpret_cast<const short8v*>(&Bs[(wn * 64 + ni * 16 + fr) * BK + kc * 8]);
            #pragma unroll
            for (int mi = 0; mi < 4; ++mi)
                acc[mi][ni] = __builtin_amdgcn_mfma_f32_16x16x32_bf16(af[mi], bfrag, acc[mi][ni], 0, 0, 0);
        }
        __syncthreads();
    }

    // ---- epilogue: store xw, accumulate totals[row] += sum_c exp(modx*cos) ----
    const int colg = lane & 15, rowg = lane >> 4;
    #pragma unroll
    for (int mi = 0; mi < 4; ++mi) {
        #pragma unroll
        for (int j = 0; j < 4; ++j) {
            const int row = wm * 64 + mi * 16 + rowg * 4 + j;
            const float mx = s_modx[row], inv = s_inv[row];
            float esum = 0.f;
            #pragma unroll
            for (int ni = 0; ni < 4; ++ni) {
                const int col = c0 + wn * 64 + ni * 16 + colg;
                const float xw = acc[mi][ni][j];
                if (col < CLASSES) {
                    out[(size_t)row * CLASSES + col] = xw;
                    float ct = fminf(fmaxf(xw * inv, -1.f), 1.f);  // inert when sane
                    esum += __expf(mx * ct);
                }
            }
            esum += __shfl_xor(esum, 1);
            esum += __shfl_xor(esum, 2);
            esum += __shfl_xor(esum, 4);
            esum += __shfl_xor(esum, 8);
            if (colg == 0) atomicAdd(&totals[row], esum);
        }
    }
}

// ---------------- K5: final epilogue (stable log-space), in-place on d_out ----------------
__global__ void final_kernel(float* __restrict__ xw, const float* __restrict__ modx,
                             const float* __restrict__ totals) {
    const int b = blockIdx.y;
    const int i = blockIdx.x * blockDim.x + threadIdx.x;   // float4 index
    if (i >= CLASSES / 4) return;
    const float mx = modx[b];
    // tot clamp: NaN->0 (fmaxf), inf->1e30; inert for correct pipeline (~1e5)
    const float tot = fminf(fmaxf(totals[b], 0.0f), 1e30f);
    const float inv_me = 1.0f / (mx + EPSV);
    float4* row = reinterpret_cast<float4*>(xw + (size_t)b * CLASSES);
    float4 v = row[i];
    float r[4] = {v.x, v.y, v.z, v.w};
    #pragma unroll
    for (int j = 0; j < 4; ++j) {
        float ct   = fminf(fmaxf(r[j] * inv_me, -1.f), 1.f);  // cos in [-1,1]; NaN->-1
        float xct  = mx * ct;                // x_cos_theta
        float ec   = expf(xct);              // e_cos (<= e^25, finite)
        float c2   = ct * ct;
        float cm   = 8.f * c2 * c2 - 8.f * c2 + 1.f;   // cos(4t)
        float psi  = -cm - 6.f;              // (-1)^3 * cm - 2*3
        float xpsi = mx * psi;               // ~ -158, exp underflows in fp32
        float den  = expf(xpsi) + (tot - ec);
        den = fmaxf(den, 1e-37f);            // floor: no log(<=0) ever
        r[j] = xpsi - logf(den);
    }
    row[i] = make_float4(r[0], r[1], r[2], r[3]);
}

extern "C" void kernel_launch(void* const* d_in, const int* in_sizes, int n_in,
                              void* d_out, int out_size, void* d_ws, size_t ws_size,
                              hipStream_t stream) {
    const float* x = (const float*)d_in[0];   // [256, 512]
    const float* W = (const float*)d_in[1];   // [512, 100000]
    float* out = (float*)d_out;               // [256, 100000]
    float* wsf = (float*)d_ws;

    unsigned short* xp = (unsigned short*)wsf;        // 256*512 bf16 = 262144 B
    float* inv_norm = wsf + 65536;                    // 512
    float* modx     = wsf + 66048;                    // 256
    float* totals   = wsf + 66304;                    // 256

    winorm_kernel<<<FEAT, 512, 0, stream>>>(W, inv_norm);
    xprep_kernel<<<BATCH, 128, 0, stream>>>(x, inv_norm, xp, modx, totals);
    gemm_kernel<<<(CLASSES + BN - 1) / BN, 512, 0, stream>>>(xp, W, modx, out, totals);
    final_kernel<<<dim3((CLASSES / 4 + 255) / 256, BATCH), 256, 0, stream>>>(out, modx, totals);
}

// Round 7
// 581.408 us; speedup vs baseline: 1.3331x; 1.0565x over previous
//
#include <hip/hip_runtime.h>
#include <math.h>

// AngularSoftmax: B=256, F=512, C=100000, M=4 (k=3), fp32 in/out.
// out[b,c] = x_psi - log(exp(x_psi) + (total_b - e_cos))   (stable log-space)
// Round 7: GEMM was LDS-bank-conflict-bound (5.3e7 conflicts; 32-way on the
// in-loop fp32->bf16 transpose scalar writes). Hoist transpose to a separate
// memory-bound pass (Wt[100000][512] bf16, fused with W-norms), GEMM stages
// both operands linearly (b128) with XOR-swizzled 16B slots -> conflict-free.
// Fallback to the round-6 path if ws_size can't hold Wt (~103 MB).

#define BATCH   256
#define FEAT    512
#define CLASSES 100000
#define EPSV    1e-6f

typedef __attribute__((ext_vector_type(8))) short short8v;   // 8 bf16 (4 VGPRs)
typedef __attribute__((ext_vector_type(4))) float f32x4;

static __device__ __forceinline__ unsigned short f32_to_bf16(float f) {
    unsigned int u = __float_as_uint(f);
    u += 0x7fffu + ((u >> 16) & 1u);     // RNE (inputs are finite)
    return (unsigned short)(u >> 16);
}

// ---------------- K1 (fast): W[512][100000] -> Wt[100000][512] bf16 + norm2 ----------------
// grid (391 c-blocks, 16 f-blocks), 256 threads. Tile: 32 f x 256 c.
__global__ __launch_bounds__(256) void transpose_kernel(const float* __restrict__ W,
                                                        unsigned short* __restrict__ Wt,
                                                        float* __restrict__ norm2) {
    __shared__ unsigned short Ls[256 * 33];   // [c_local][f_local], stride 33 (pad)
    __shared__ float nrm[32];
    const int tid = threadIdx.x;
    const int c0 = blockIdx.x * 256;
    const int f0 = blockIdx.y * 32;
    if (tid < 32) nrm[tid] = 0.f;
    __syncthreads();

    const int cg = tid & 63;            // lane: 64 col-groups of 4 (coalesced float4)
    const int fb = tid >> 6;            // wave: 4 f's per round
    #pragma unroll
    for (int r = 0; r < 8; ++r) {
        const int fid = fb + r * 4;     // 0..31, unique per (wave, round)
        const int c = c0 + cg * 4;
        float4 v = make_float4(0.f, 0.f, 0.f, 0.f);
        const float* wr = W + (size_t)(f0 + fid) * CLASSES;
        if (c + 3 < CLASSES) {
            v = *reinterpret_cast<const float4*>(wr + c);
        } else {
            if (c + 0 < CLASSES) v.x = wr[c + 0];
            if (c + 1 < CLASSES) v.y = wr[c + 1];
            if (c + 2 < CLASSES) v.z = wr[c + 2];
            if (c + 3 < CLASSES) v.w = wr[c + 3];
        }
        float sq = v.x * v.x + v.y * v.y + v.z * v.z + v.w * v.w;
        #pragma unroll
        for (int off = 32; off > 0; off >>= 1) sq += __shfl_down(sq, off);
        if ((tid & 63) == 0) nrm[fid] += sq;       // exclusive owner (wave,round)
        Ls[(cg * 4 + 0) * 33 + fid] = f32_to_bf16(v.x);
        Ls[(cg * 4 + 1) * 33 + fid] = f32_to_bf16(v.y);
        Ls[(cg * 4 + 2) * 33 + fid] = f32_to_bf16(v.z);
        Ls[(cg * 4 + 3) * 33 + fid] = f32_to_bf16(v.w);
    }
    __syncthreads();

    // store: rows of Wt; 8 lanes x b64 = 64B per row, 8 rows per wave-instr
    const int fg = tid & 7;             // 4 f's each
    const int cl0 = tid >> 3;           // 0..31
    #pragma unroll
    for (int r = 0; r < 8; ++r) {
        const int cl = cl0 + r * 32;
        const int c = c0 + cl;
        if (c < CLASSES) {
            ushort4 o;
            o.x = Ls[cl * 33 + fg * 4 + 0];
            o.y = Ls[cl * 33 + fg * 4 + 1];
            o.z = Ls[cl * 33 + fg * 4 + 2];
            o.w = Ls[cl * 33 + fg * 4 + 3];
            *reinterpret_cast<ushort4*>(Wt + (size_t)c * FEAT + f0 + fg * 4) = o;
        }
    }
    if (tid < 32) atomicAdd(&norm2[f0 + tid], nrm[tid]);
}

// ---------------- K1 (fallback): norm2[f] = sum_c W[f,c]^2 ----------------
__global__ __launch_bounds__(512) void winorm_kernel(const float* __restrict__ W,
                                                     float* __restrict__ norm2) {
    const int f = blockIdx.x;
    const float4* row = reinterpret_cast<const float4*>(W + (size_t)f * CLASSES);
    float s = 0.f;
    for (int i = threadIdx.x; i < CLASSES / 4; i += blockDim.x) {
        float4 v = row[i];
        s += v.x * v.x + v.y * v.y + v.z * v.z + v.w * v.w;
    }
    __shared__ float red[8];
    #pragma unroll
    for (int off = 32; off > 0; off >>= 1) s += __shfl_down(s, off);
    const int lane = threadIdx.x & 63, wid = threadIdx.x >> 6;
    if (lane == 0) red[wid] = s;
    __syncthreads();
    if (threadIdx.x == 0) {
        float t = 0.f;
        #pragma unroll
        for (int i = 0; i < 8; ++i) t += red[i];
        norm2[f] = t;
    }
}

// ---------------- K2: xp = bf16(x * rsqrt(norm2)), modx[b] = ||x_b|| ----------------
__global__ void xprep_kernel(const float* __restrict__ x, const float* __restrict__ norm2,
                             unsigned short* __restrict__ xp, float* __restrict__ modx) {
    const int b = blockIdx.x;      // 256 blocks
    const int t = threadIdx.x;     // 128 threads, one float4 each
    float4 xv = reinterpret_cast<const float4*>(x + (size_t)b * FEAT)[t];
    float s = xv.x * xv.x + xv.y * xv.y + xv.z * xv.z + xv.w * xv.w;
    __shared__ float red[2];
    #pragma unroll
    for (int off = 32; off > 0; off >>= 1) s += __shfl_down(s, off);
    const int lane = t & 63, wid = t >> 6;
    if (lane == 0) red[wid] = s;
    __syncthreads();
    if (t == 0) modx[b] = sqrtf(red[0] + red[1]);
    float4 nv = reinterpret_cast<const float4*>(norm2)[t];
    ushort4 o;
    o.x = f32_to_bf16(xv.x * rsqrtf(nv.x));
    o.y = f32_to_bf16(xv.y * rsqrtf(nv.y));
    o.z = f32_to_bf16(xv.z * rsqrtf(nv.z));
    o.w = f32_to_bf16(xv.w * rsqrtf(nv.w));
    reinterpret_cast<ushort4*>(xp + (size_t)b * FEAT)[t] = o;
}

// ---------------- K3 (fast): MFMA GEMM from Wt, both operands linear+swizzled ----------------
// BM=256, BN=128, BK=64. 512 threads = 8 waves (4M x 2N). LDS rows are 128B;
// 16B slot s of row r stored at slot (s ^ (r&7)) -> bank-balanced b128 reads.
__global__ __launch_bounds__(512) void gemm_fast(
        const unsigned short* __restrict__ xp,  // [256][512] bf16
        const unsigned short* __restrict__ Wt,  // [100000][512] bf16
        const float* __restrict__ modx,
        float* __restrict__ out,                // [256][100000] <- xw
        float* __restrict__ totals) {
#define BKF 64
    __shared__ __align__(16) unsigned short As[BATCH * BKF];
    __shared__ __align__(16) unsigned short Bs[128 * BKF];
    __shared__ float s_modx[BATCH], s_inv[BATCH];

    const int tid = threadIdx.x, wave = tid >> 6, lane = tid & 63;
    const int c0 = blockIdx.x * 128;
    if (tid < BATCH) {
        float m = modx[tid];
        s_modx[tid] = m;
        s_inv[tid]  = 1.0f / (m + EPSV);
    }
    const int wm = wave >> 1, wn = wave & 1;
    const int qa = tid & 7;        // 16B chunk (8 bf16) within a 128B k-row
    const int rrow = tid >> 3;     // 0..63

    f32x4 acc[4][4];
    #pragma unroll
    for (int i = 0; i < 4; ++i)
        #pragma unroll
        for (int j = 0; j < 4; ++j) acc[i][j] = (f32x4){0.f, 0.f, 0.f, 0.f};

    for (int k0 = 0; k0 < FEAT; k0 += BKF) {
        #pragma unroll
        for (int rnd = 0; rnd < 4; ++rnd) {     // A: 256 rows
            const int rr = rrow + rnd * 64;
            short8v v = *reinterpret_cast<const short8v*>(xp + (size_t)rr * FEAT + k0 + qa * 8);
            *reinterpret_cast<short8v*>(&As[rr * BKF + ((qa ^ (rr & 7)) << 3)]) = v;
        }
        #pragma unroll
        for (int rnd = 0; rnd < 2; ++rnd) {     // B: 128 cols
            const int col = rrow + rnd * 64;
            const int gc = c0 + col;
            short8v v = (short8v){0, 0, 0, 0, 0, 0, 0, 0};
            if (gc < CLASSES)
                v = *reinterpret_cast<const short8v*>(Wt + (size_t)gc * FEAT + k0 + qa * 8);
            *reinterpret_cast<short8v*>(&Bs[col * BKF + ((qa ^ (col & 7)) << 3)]) = v;
        }
        __syncthreads();
        const int fr = lane & 15, kc = lane >> 4;
        #pragma unroll
        for (int kw = 0; kw < 2; ++kw) {
            const int slot = kw * 4 + kc;
            short8v af[4], bfv[4];
            #pragma unroll
            for (int mi = 0; mi < 4; ++mi) {
                const int row = wm * 64 + mi * 16 + fr;
                af[mi] = *reinterpret_cast<const short8v*>(&As[row * BKF + ((slot ^ (row & 7)) << 3)]);
            }
            #pragma unroll
            for (int ni = 0; ni < 4; ++ni) {
                const int row = wn * 64 + ni * 16 + fr;
                bfv[ni] = *reinterpret_cast<const short8v*>(&Bs[row * BKF + ((slot ^ (row & 7)) << 3)]);
            }
            #pragma unroll
            for (int ni = 0; ni < 4; ++ni)
                #pragma unroll
                for (int mi = 0; mi < 4; ++mi)
                    acc[mi][ni] = __builtin_amdgcn_mfma_f32_16x16x32_bf16(af[mi], bfv[ni], acc[mi][ni], 0, 0, 0);
        }
        __syncthreads();
    }

    const int colg = lane & 15, rowg = lane >> 4;
    #pragma unroll
    for (int mi = 0; mi < 4; ++mi) {
        #pragma unroll
        for (int j = 0; j < 4; ++j) {
            const int row = wm * 64 + mi * 16 + rowg * 4 + j;
            const float mx = s_modx[row], inv = s_inv[row];
            float esum = 0.f;
            #pragma unroll
            for (int ni = 0; ni < 4; ++ni) {
                const int col = c0 + wn * 64 + ni * 16 + colg;
                const float xw = acc[mi][ni][j];
                if (col < CLASSES) {
                    out[(size_t)row * CLASSES + col] = xw;
                    float ct = fminf(fmaxf(xw * inv, -1.f), 1.f);
                    esum += __expf(mx * ct);
                }
            }
            esum += __shfl_xor(esum, 1);
            esum += __shfl_xor(esum, 2);
            esum += __shfl_xor(esum, 4);
            esum += __shfl_xor(esum, 8);
            if (colg == 0) atomicAdd(&totals[row], esum);
        }
    }
#undef BKF
}

// ---------------- K3 (fallback): round-6 passing GEMM (reads W fp32) ----------------
#define BN 128
#define BK 32
__global__ __launch_bounds__(512) void gemm_old(
        const unsigned short* __restrict__ xp, const float* __restrict__ W,
        const float* __restrict__ modx, float* __restrict__ out, float* __restrict__ totals) {
    __shared__ __align__(16) unsigned short As[BATCH * BK];
    __shared__ __align__(16) unsigned short Bs[BN * BK];
    __shared__ float s_modx[BATCH], s_inv[BATCH];
    const int tid = threadIdx.x, wave = tid >> 6, lane = tid & 63;
    const int c0 = blockIdx.x * BN;
    if (tid < BATCH) {
        float m = modx[tid];
        s_modx[tid] = m;
        s_inv[tid]  = 1.0f / (m + EPSV);
    }
    const int wm = wave >> 1, wn = wave & 1;
    const int ra = tid >> 2, qa = tid & 3;
    const int bc4 = tid & 31, bk0 = tid >> 5;
    int cbase = c0 + bc4 * 4;
    if (cbase > CLASSES - 4) cbase = CLASSES - 4;
    f32x4 acc[4][4];
    #pragma unroll
    for (int i = 0; i < 4; ++i)
        #pragma unroll
        for (int j = 0; j < 4; ++j) acc[i][j] = (f32x4){0.f, 0.f, 0.f, 0.f};
    for (int k0 = 0; k0 < FEAT; k0 += BK) {
        #pragma unroll
        for (int rnd = 0; rnd < 2; ++rnd) {
            int r = rnd * 128 + ra;
            short8v v = *reinterpret_cast<const short8v*>(xp + (size_t)r * FEAT + k0 + qa * 8);
            *reinterpret_cast<short8v*>(&As[r * BK + qa * 8]) = v;
        }
        #pragma unroll
        for (int rnd = 0; rnd < 2; ++rnd) {
            int kk = bk0 + rnd * 16;
            float4 wv = *reinterpret_cast<const float4*>(W + (size_t)(k0 + kk) * CLASSES + cbase);
            Bs[(bc4 * 4 + 0) * BK + kk] = f32_to_bf16(wv.x);
            Bs[(bc4 * 4 + 1) * BK + kk] = f32_to_bf16(wv.y);
            Bs[(bc4 * 4 + 2) * BK + kk] = f32_to_bf16(wv.z);
            Bs[(bc4 * 4 + 3) * BK + kk] = f32_to_bf16(wv.w);
        }
        __syncthreads();
        const int fr = lane & 15, kc = lane >> 4;
        short8v af[4];
        #pragma unroll
        for (int mi = 0; mi < 4; ++mi)
            af[mi] = *reinterpret_cast<const short8v*>(&As[(wm * 64 + mi * 16 + fr) * BK + kc * 8]);
        #pragma unroll
        for (int ni = 0; ni < 4; ++ni) {
            short8v bfrag = *reinterpret_cast<const short8v*>(&Bs[(wn * 64 + ni * 16 + fr) * BK + kc * 8]);
            #pragma unroll
            for (int mi = 0; mi < 4; ++mi)
                acc[mi][ni] = __builtin_amdgcn_mfma_f32_16x16x32_bf16(af[mi], bfrag, acc[mi][ni], 0, 0, 0);
        }
        __syncthreads();
    }
    const int colg = lane & 15, rowg = lane >> 4;
    #pragma unroll
    for (int mi = 0; mi < 4; ++mi) {
        #pragma unroll
        for (int j = 0; j < 4; ++j) {
            const int row = wm * 64 + mi * 16 + rowg * 4 + j;
            const float mx = s_modx[row], inv = s_inv[row];
            float esum = 0.f;
            #pragma unroll
            for (int ni = 0; ni < 4; ++ni) {
                const int col = c0 + wn * 64 + ni * 16 + colg;
                const float xw = acc[mi][ni][j];
                if (col < CLASSES) {
                    out[(size_t)row * CLASSES + col] = xw;
                    float ct = fminf(fmaxf(xw * inv, -1.f), 1.f);
                    esum += __expf(mx * ct);
                }
            }
            esum += __shfl_xor(esum, 1);
            esum += __shfl_xor(esum, 2);
            esum += __shfl_xor(esum, 4);
            esum += __shfl_xor(esum, 8);
            if (colg == 0) atomicAdd(&totals[row], esum);
        }
    }
}

// ---------------- K5: final epilogue (stable log-space), in-place on d_out ----------------
__global__ void final_kernel(float* __restrict__ xw, const float* __restrict__ modx,
                             const float* __restrict__ totals) {
    const int b = blockIdx.y;
    const int i = blockIdx.x * blockDim.x + threadIdx.x;
    if (i >= CLASSES / 4) return;
    const float mx = modx[b];
    const float tot = fminf(fmaxf(totals[b], 0.0f), 1e30f);
    const float inv_me = 1.0f / (mx + EPSV);
    float4* row = reinterpret_cast<float4*>(xw + (size_t)b * CLASSES);
    float4 v = row[i];
    float r[4] = {v.x, v.y, v.z, v.w};
    #pragma unroll
    for (int j = 0; j < 4; ++j) {
        float ct   = fminf(fmaxf(r[j] * inv_me, -1.f), 1.f);
        float xct  = mx * ct;
        float ec   = expf(xct);
        float c2   = ct * ct;
        float cm   = 8.f * c2 * c2 - 8.f * c2 + 1.f;
        float psi  = -cm - 6.f;
        float xpsi = mx * psi;
        float den  = expf(xpsi) + (tot - ec);
        den = fmaxf(den, 1e-37f);
        r[j] = xpsi - logf(den);
    }
    row[i] = make_float4(r[0], r[1], r[2], r[3]);
}

extern "C" void kernel_launch(void* const* d_in, const int* in_sizes, int n_in,
                              void* d_out, int out_size, void* d_ws, size_t ws_size,
                              hipStream_t stream) {
    const float* x = (const float*)d_in[0];
    const float* W = (const float*)d_in[1];
    float* out = (float*)d_out;
    char* wsb = (char*)d_ws;

    unsigned short* xp = (unsigned short*)wsb;            // 262144 B
    float* norm2  = (float*)(wsb + 262144);               // 2048 B
    float* modx   = (float*)(wsb + 264192);               // 1024 B
    float* totals = (float*)(wsb + 265216);               // 1024 B
    unsigned short* Wt = (unsigned short*)(wsb + 266240); // 102,400,000 B
    const size_t need = 266240u + (size_t)CLASSES * FEAT * 2u;

    hipMemsetAsync(norm2, 0, 4096, stream);   // zero norm2 + totals (capture-safe)

    if (ws_size >= need) {
        transpose_kernel<<<dim3((CLASSES + 255) / 256, FEAT / 32), 256, 0, stream>>>(W, Wt, norm2);
        xprep_kernel<<<BATCH, 128, 0, stream>>>(x, norm2, xp, modx);
        gemm_fast<<<(CLASSES + 127) / 128, 512, 0, stream>>>(xp, Wt, modx, out, totals);
    } else {
        winorm_kernel<<<FEAT, 512, 0, stream>>>(W, norm2);
        xprep_kernel<<<BATCH, 128, 0, stream>>>(x, norm2, xp, modx);
        gemm_old<<<(CLASSES + BN - 1) / BN, 512, 0, stream>>>(xp, W, modx, out, totals);
    }
    final_kernel<<<dim3((CLASSES / 4 + 255) / 256, BATCH), 256, 0, stream>>>(out, modx, totals);
}